// Round 4
// baseline (2118.529 us; speedup 1.0000x reference)
//
#include <hip/hip_runtime.h>

#define DEV_INLINE __device__ __forceinline__
typedef unsigned long long ull;

// ---------------- compile-time helpers ----------------
constexpr int roundup4(int v){ return (v+3)&~3; }
constexpr int lds_stride(int win){
  int s = roundup4(win);
  if (s % 16 == 0) s += 4;
  return s;
}

// ---------------- prep: all weight transposes in one launch ----------------
__global__ void prep_all(const float* __restrict__ enc_w, float* __restrict__ encTg,
                         const float* __restrict__ dec_w, float* __restrict__ decT,
                         const float* __restrict__ red_w, float* __restrict__ redT,
                         const float* __restrict__ fc_w,  float* __restrict__ fcT,
                         const float* __restrict__ c1w, float* __restrict__ WT1,
                         const float* __restrict__ c2w, float* __restrict__ WT2,
                         const float* __restrict__ c3w, float* __restrict__ WT3,
                         const float* __restrict__ c4w, float* __restrict__ WT4,
                         const float* __restrict__ c5w, float* __restrict__ WT5)
{
  const int b = blockIdx.x, t = threadIdx.x;
  auto t2 = [&](const float* A, float* AT, int R, int C, int base){
    int i = (b-base)*256 + t; if (i < R*C){ int r=i%R, c=i/R; AT[i] = A[r*C+c]; }
  };
  auto tw = [&](const float* W, float* WT, int O, int I, int base){
    int i = (b-base)*256 + t;
    if (i < O*I){ int o=i%O, ii=i/O;
      const float* s = W + (size_t)(o*I+ii)*9;
      #pragma unroll
      for (int kk=0;kk<9;++kk) WT[(kk*I+ii)*O+o] = s[kk]; }
  };
  if      (b < 27)  t2(enc_w, encTg, 256, 27, 0);
  else if (b < 54)  t2(dec_w, decT, 27, 256, 27);
  else if (b < 118) t2(red_w, redT, 64, 256, 54);
  else if (b < 518) t2(fc_w,  fcT, 100, 1024, 118);
  else if (b < 542) tw(c1w, WT1, 96, 64, 518);
  else if (b < 590) tw(c2w, WT2, 128, 96, 542);
  else if (b < 670) tw(c3w, WT3, 160, 128, 590);
  else if (b < 790) tw(c4w, WT4, 192, 160, 670);
  else              tw(c5w, WT5, 256, 192, 790);
}

// ---------------- A1: enc conv + early-exit topk + compact survivors ----------------
// grid (15, 256) = (oh-pair, b); 512 threads (8 waves) share one weight tile ->
// 4 blocks/CU = 32 waves/CU. Writes exact (f32 val, u8 idx) survivor lists:
// svg_v[32][230400], svg_i[32][230400].
__global__ __launch_bounds__(512, 8) void stage_a1(
    const float* __restrict__ encTg, const float* __restrict__ enc_b,
    const float* __restrict__ x, const int* __restrict__ kp,
    float* __restrict__ svg_v, unsigned char* __restrict__ svg_i)
{
  __shared__ float4 encT4[27*64];          // 27648 B
  __shared__ float  rows[12*32];           // 1536 B: x rows oh0..oh0+3, [ci*4+r][32]
  __shared__ float  svf[60*33];            // 7920 B (stride 33: conflict-free col reads)
  __shared__ unsigned char svi[60*33];     // 1980 B

  const int t = threadIdx.x, bx = blockIdx.x, b = blockIdx.y;
  const int oh0 = 2*bx;
  const int k = __builtin_amdgcn_readfirstlane(*kp);
  const int wid = t>>6, lane = t&63;
  float* encT = (float*)encT4;

  for (int e=t; e<6912; e+=512) encT[e] = encTg[e];
  for (int e=t; e<384; e+=512){
    int ci = e/128, r = (e>>5)&3, xx = e&31;
    rows[(ci*4+r)*32+xx] = x[((b*3+ci)*32 + (oh0+r))*32 + xx];
  }
  for (int e=t; e<1980; e+=512){ svf[e]=0.f; svi[e]=0; }
  __syncthreads();

  const float4 eb = ((const float4*)enc_b)[lane];

  auto cnt4 = [&](unsigned c, unsigned u0, unsigned u1, unsigned u2, unsigned u3)->int{
    return __popcll(__ballot(u0>=c)) + __popcll(__ballot(u1>=c))
         + __popcll(__ballot(u2>=c)) + __popcll(__ballot(u3>=c));
  };
  auto compact = [&](float v0,float v1,float v2,float v3,
                     unsigned u0,unsigned u1,unsigned u2,unsigned u3,
                     unsigned th, int pi){
    bool k0=u0>=th, k1=u1>=th, k2=u2>=th, k3=u3>=th;
    ull B0=__ballot(k0), B1=__ballot(k1), B2=__ballot(k2), B3=__ballot(k3);
    ull below=(1ull<<lane)-1ull;
    int n0=__popcll(B0), n1=__popcll(B1), n2=__popcll(B2);
    int o0=__popcll(B0&below);
    int o1=n0+__popcll(B1&below);
    int o2=n0+n1+__popcll(B2&below);
    int o3=n0+n1+n2+__popcll(B3&below);
    float* sf = &svf[pi*33]; unsigned char* si = &svi[pi*33];
    if (k0&&o0<32){ sf[o0]=v0; si[o0]=(unsigned char)(4*lane+0); }
    if (k1&&o1<32){ sf[o1]=v1; si[o1]=(unsigned char)(4*lane+1); }
    if (k2&&o2<32){ sf[o2]=v2; si[o2]=(unsigned char)(4*lane+2); }
    if (k3&&o3<32){ sf[o3]=v3; si[o3]=(unsigned char)(4*lane+3); }
  };

  for (int pp = wid; pp < 30; pp += 8){
    const int rr = pp/15, j = pp - rr*15;
    const int ow0 = 2*j, ow1 = ow0+1;
    const int pi0 = rr*30 + ow0;

    float a0=eb.x,a1=eb.y,a2=eb.z,a3=eb.w;
    float c0=eb.x,c1=eb.y,c2=eb.z,c3=eb.w;
    #pragma unroll
    for (int ci=0; ci<3; ++ci)
      #pragma unroll
      for (int i=0;i<3;++i){
        const int rbase = (ci*4 + rr + i)*32;
        float p0 = rows[rbase+ow0+0], p1 = rows[rbase+ow0+1];
        float p2 = rows[rbase+ow0+2], p3 = rows[rbase+ow0+3];
        float4 w0 = encT4[(ci*9+i*3+0)*64 + lane];
        float4 w1 = encT4[(ci*9+i*3+1)*64 + lane];
        float4 w2 = encT4[(ci*9+i*3+2)*64 + lane];
        a0=fmaf(w0.x,p0,a0); a1=fmaf(w0.y,p0,a1); a2=fmaf(w0.z,p0,a2); a3=fmaf(w0.w,p0,a3);
        c0=fmaf(w0.x,p1,c0); c1=fmaf(w0.y,p1,c1); c2=fmaf(w0.z,p1,c2); c3=fmaf(w0.w,p1,c3);
        a0=fmaf(w1.x,p1,a0); a1=fmaf(w1.y,p1,a1); a2=fmaf(w1.z,p1,a2); a3=fmaf(w1.w,p1,a3);
        c0=fmaf(w1.x,p2,c0); c1=fmaf(w1.y,p2,c1); c2=fmaf(w1.z,p2,c2); c3=fmaf(w1.w,p2,c3);
        a0=fmaf(w2.x,p2,a0); a1=fmaf(w2.y,p2,a1); a2=fmaf(w2.z,p2,a2); a3=fmaf(w2.w,p2,a3);
        c0=fmaf(w2.x,p3,c0); c1=fmaf(w2.y,p3,c1); c2=fmaf(w2.z,p3,c2); c3=fmaf(w2.w,p3,c3);
      }

    unsigned A0=__float_as_uint(a0)&0x7fffffffu, A1=__float_as_uint(a1)&0x7fffffffu;
    unsigned A2=__float_as_uint(a2)&0x7fffffffu, A3=__float_as_uint(a3)&0x7fffffffu;
    unsigned C0=__float_as_uint(c0)&0x7fffffffu, C1=__float_as_uint(c1)&0x7fffffffu;
    unsigned C2=__float_as_uint(c2)&0x7fffffffu, C3=__float_as_uint(c3)&0x7fffffffu;

    // dual exact kth-largest-|v|, radix-2 with EARLY EXIT:
    // if exactly k values >= th, {a>=th} == {a>=kth} (mask-exact) -> stop.
    unsigned thA=0, thB=0;
    int dA=0, dB=0;
    for (int bit=30; bit>=0; --bit){
      if (!dA){
        unsigned c = thA | (1u<<bit);
        int n = cnt4(c,A0,A1,A2,A3);
        if (n>=k) thA=c;
        if (n==k) dA=1;
      }
      if (!dB){
        unsigned c = thB | (1u<<bit);
        int n = cnt4(c,C0,C1,C2,C3);
        if (n>=k) thB=c;
        if (n==k) dB=1;
      }
      if (dA & dB) break;
    }

    compact(a0,a1,a2,a3, A0,A1,A2,A3, thA, pi0);
    compact(c0,c1,c2,c3, C0,C1,C2,C3, thB, pi0+1);
  }
  __syncthreads();

  // coalesced store: global layout [slot][pos]; LDS read svf[pi*33+jj] with pi
  // fastest across lanes -> banks (pi+jj)%32 spread, conflict-free.
  const size_t gbase = (size_t)b*900 + (size_t)bx*60;
  for (int e=t; e<1920; e+=512){
    int jj = e/60, pi = e - jj*60;
    svg_v[(size_t)jj*230400 + gbase + pi] = svf[pi*33+jj];
    svg_i[(size_t)jj*230400 + gbase + pi] = svi[pi*33+jj];
  }
}

// ---------------- A2: dec + sigmoid + aux (position-per-lane, decT in LDS) ----------------
__global__ __launch_bounds__(256, 5) void stage_a2(
    const float* __restrict__ svg_v, const unsigned char* __restrict__ svg_i,
    const float* __restrict__ decT, const float* __restrict__ dec_b,
    const float* __restrict__ x, float* __restrict__ auxp)
{
  __shared__ float decl[6912];   // [idx][o], stride 27 (odd -> banks spread)
  __shared__ float redbuf[256];
  const int t = threadIdx.x;
  for (int e=t; e<6912; e+=256) decl[e] = decT[e];
  __syncthreads();

  const int pos = blockIdx.x*256 + t;
  const int b = pos/900, rem = pos - b*900;
  const int oh = rem/30, ow = rem - (rem/30)*30;

  float d[27];
  #pragma unroll
  for (int o=0;o<27;++o) d[o] = dec_b[o];
  for (int jj=0; jj<32; ++jj){
    float v  = svg_v[(size_t)jj*230400 + pos];
    int  idx = (int)svg_i[(size_t)jj*230400 + pos];
    const float* wr = decl + idx*27;
    #pragma unroll
    for (int o=0;o<27;++o) d[o] = fmaf(v, wr[o], d[o]);
  }
  float acc = 0.f;
  #pragma unroll
  for (int o=0;o<27;++o){
    int ci = o/9, r2 = (o - ci*9)/3, c2 = o%3;
    float tg = x[((b*3+ci)*32 + (oh+r2))*32 + (ow+c2)];
    float dv = 1.f/(1.f + __expf(-d[o]));
    float df = tg - dv;
    acc = fmaf(df, df, acc);
  }
  redbuf[t]=acc; __syncthreads();
  for (int off=128; off; off>>=1){ if (t<off) redbuf[t]+=redbuf[t+off]; __syncthreads(); }
  if (t==0) auxp[blockIdx.x] = redbuf[0];
}

__global__ void aux_reduce(const float* __restrict__ p, float* __restrict__ outp){
  __shared__ float s[256];
  int t = threadIdx.x; float a=0.f;
  for (int i=t; i<900; i+=256) a += p[i];
  s[t]=a; __syncthreads();
  for (int off=128; off; off>>=1){ if (t<off) s[t]+=s[t+off]; __syncthreads(); }
  if (t==0) outp[25856] = s[0] / 6220800.0f;
}

// ---------------- A3: red -> h0 channel-major (position-per-lane, redT in LDS) ----------------
__global__ __launch_bounds__(512, 4) void stage_a3(
    const float* __restrict__ svg_v, const unsigned char* __restrict__ svg_i,
    const float* __restrict__ redT, const float* __restrict__ red_b,
    float* __restrict__ h0T)
{
  __shared__ float redl[256*65];   // [idx][o] stride 65 -> bank (idx+o)%32
  const int t = threadIdx.x;
  for (int e=t; e<16384; e+=512) redl[(e>>6)*65 + (e&63)] = redT[e];
  __syncthreads();

  const size_t pos = (size_t)blockIdx.x*512 + t;
  float v[32]; int a[32];
  #pragma unroll
  for (int jj=0;jj<32;++jj) v[jj] = svg_v[(size_t)jj*230400 + pos];
  #pragma unroll
  for (int jj=0;jj<32;++jj) a[jj] = (int)svg_i[(size_t)jj*230400 + pos]*65;

  #pragma unroll 2
  for (int o=0;o<64;++o){
    float acc0 = red_b[o], acc1 = 0.f;
    #pragma unroll
    for (int jj=0;jj<32;jj+=2){
      acc0 = fmaf(v[jj],   redl[a[jj]+o],   acc0);
      acc1 = fmaf(v[jj+1], redl[a[jj+1]+o], acc1);
    }
    h0T[(size_t)o*230400 + pos] = acc0 + acc1;
  }
}

// ---------------- BN stats ----------------
// channel-major variant for h0T: one block per channel
__global__ void bn_cm64(const float* __restrict__ h0T, float* __restrict__ psum,
                        float* __restrict__ psq){
  __shared__ float ls[256], lq[256];
  const int t = threadIdx.x;
  const float4* p = (const float4*)(h0T + (size_t)blockIdx.x*230400);
  float s=0.f, q=0.f;
  for (int i=t; i<57600; i+=256){
    float4 f = p[i];
    s += f.x+f.y+f.z+f.w;
    q = fmaf(f.x,f.x,q); q = fmaf(f.y,f.y,q); q = fmaf(f.z,f.z,q); q = fmaf(f.w,f.w,q);
  }
  ls[t]=s; lq[t]=q; __syncthreads();
  for (int off=128; off; off>>=1){
    if (t<off){ ls[t]+=ls[t+off]; lq[t]+=lq[t+off]; } __syncthreads();
  }
  if (t==0){ psum[blockIdx.x]=ls[0]; psq[blockIdx.x]=lq[0]; }
}

template<int C, int BD>
__global__ void bn_partial(const float* __restrict__ in, float* __restrict__ psum,
                           float* __restrict__ psq, int npos){
  constexpr int GPB = BD / C;
  const int t = threadIdx.x;
  const int c = t % C, g = t / C;
  float s=0.f, q=0.f;
  for (int i = blockIdx.x*GPB + g; i < npos; i += gridDim.x*GPB){
    float v = in[i*C + c];
    s += v; q = fmaf(v, v, q);
  }
  __shared__ float ls[BD], lq[BD];
  ls[t]=s; lq[t]=q; __syncthreads();
  for (int off=BD/2; off>=C; off>>=1){
    if (t<off){ ls[t]+=ls[t+off]; lq[t]+=lq[t+off]; }
    __syncthreads();
  }
  if (t<C){ psum[blockIdx.x*C+t]=ls[t]; psq[blockIdx.x*C+t]=lq[t]; }
}

template<int C>
__global__ void bn_final(const float* __restrict__ ps, const float* __restrict__ pq,
                         const float* __restrict__ g, const float* __restrict__ b2,
                         float* __restrict__ sc, float* __restrict__ sh, float inv_n, int G){
  int t = threadIdx.x;
  if (t >= C) return;
  float s=0.f, q=0.f;
  for (int i=0;i<G;++i){ s += ps[i*C+t]; q += pq[i*C+t]; }
  float m = s*inv_n;
  float v = fmaf(q, inv_n, -m*m);
  float rs = rsqrtf(v + 1e-5f);
  float scale = g[t]*rs;
  sc[t] = scale;
  sh[t] = fmaf(-m, scale, b2[t]);
}

// ---------------- generic 3x3 valid conv, fused BN+ReLU in, optional maxpool ----------------
template<int CIN,int COUT,int HIN,int WIN,bool POOL,int NPOS>
DEV_INLINE void conv_compute(const float* lds, const float* __restrict__ wt,
                             const float* __restrict__ bias, float* __restrict__ out,
                             int b, int orow, int iw0, int co, bool cok)
{
  constexpr int S = lds_stride(WIN);
  constexpr int NROWS = POOL ? 4 : 3;
  constexpr int HC = HIN-2, WC = WIN-2;
  constexpr int IVL = roundup4(NPOS+2);
  float acc0[NPOS], acc1[POOL?NPOS:1];
  const float bv = bias[co];
  #pragma unroll
  for (int p=0;p<NPOS;++p) acc0[p]=bv;
  if (POOL){
    #pragma unroll
    for (int p=0;p<NPOS;++p) acc1[p]=bv;
  }
  for (int ci=0; ci<CIN; ++ci){
    #pragma unroll
    for (int r=0;r<NROWS;++r){
      float iv[IVL];
      const float4* rp = (const float4*)(lds + (r*CIN+ci)*S + iw0);
      #pragma unroll
      for (int q=0;q<IVL/4;++q){
        float4 f = rp[q];
        iv[4*q+0]=f.x; iv[4*q+1]=f.y; iv[4*q+2]=f.z; iv[4*q+3]=f.w;
      }
      #pragma unroll
      for (int kw=0;kw<3;++kw){
        if (!POOL || r < 3){
          float w = wt[((r*3+kw)*CIN+ci)*COUT + co];
          #pragma unroll
          for (int p=0;p<NPOS;++p) acc0[p] = fmaf(iv[p+kw], w, acc0[p]);
        }
        if (POOL && r >= 1){
          float w = wt[(((r-1)*3+kw)*CIN+ci)*COUT + co];
          #pragma unroll
          for (int p=0;p<NPOS;++p) acc1[p] = fmaf(iv[p+kw], w, acc1[p]);
        }
      }
    }
  }
  if (!cok) return;
  if (POOL){
    constexpr int HP=HC/2, WP=WC/2;
    #pragma unroll
    for (int q=0;q<NPOS/2;++q){
      float m = fmaxf(fmaxf(acc0[2*q],acc0[2*q+1]), fmaxf(acc1[2*q],acc1[2*q+1]));
      out[((b*HP + orow)*WP + (iw0>>1) + q)*COUT + co] = m;
    }
  } else {
    #pragma unroll
    for (int p=0;p<NPOS;++p)
      out[((b*HC + orow)*WC + iw0 + p)*COUT + co] = acc0[p];
  }
}

template<int CIN,int COUT,int HIN,int WIN,bool POOL,bool CMIN>
__global__ __launch_bounds__(256) void conv3x3(
    const float* __restrict__ in, const float* __restrict__ wt,
    const float* __restrict__ bias, const float* __restrict__ scale,
    const float* __restrict__ shift, float* __restrict__ out)
{
  constexpr int WC = WIN-2;
  constexpr int NROWS = POOL ? 4 : 3;
  constexpr int S = lds_stride(WIN);
  constexpr size_t NPIX = (size_t)256*HIN*WIN;
  __shared__ float4 lds4[(NROWS*CIN*S)/4];
  float* lds = (float*)lds4;

  const int b = blockIdx.y, orow = blockIdx.x;
  const int ih0 = POOL ? 2*orow : orow;
  const float* src = in + ((long)(b*HIN + ih0))*WIN*CIN;
  for (int e = threadIdx.x; e < NROWS*WIN*CIN; e += 256){
    int c, iw, r; float v;
    if constexpr (CMIN){
      iw = e % WIN; int rest = e / WIN; c = rest % CIN; r = rest / CIN;
      v = in[(size_t)c*NPIX + ((size_t)b*HIN + ih0 + r)*WIN + iw];
    } else {
      c = e % CIN; int rest = e / CIN; iw = rest % WIN; r = rest / WIN;
      v = src[e];
    }
    v = fmaxf(fmaf(v, scale[c], shift[c]), 0.f);
    lds[(r*CIN + c)*S + iw] = v;
  }
  __syncthreads();

  const int wid = threadIdx.x>>6, lane = threadIdx.x&63;
  constexpr int NCHUNK = (COUT+63)/64;
  constexpr int NSTRIP = (NCHUNK<=2 && WC>4) ? 2 : 1;
  constexpr int NPOS0  = (NSTRIP==2) ? ((WC/2+3)&~3) : WC;
  if (wid >= NCHUNK*NSTRIP) return;
  int chunk, strip;
  if (NSTRIP==2){ chunk = wid & 1; strip = wid >> 1; } else { chunk = wid; strip = 0; }
  const int co = chunk*64 + lane;
  const bool cok = co < COUT;
  const int coc = cok ? co : (COUT-1);
  if (strip==0){
    conv_compute<CIN,COUT,HIN,WIN,POOL,NPOS0>(lds, wt, bias, out, b, orow, 0, coc, cok);
  } else {
    if constexpr (NSTRIP==2){
      constexpr int NPOS1 = WC - NPOS0;
      conv_compute<CIN,COUT,HIN,WIN,POOL,NPOS1>(lds, wt, bias, out, b, orow, NPOS0, coc, cok);
    }
  }
}

// ---------------- final: bnc + FC + argmax ----------------
__global__ __launch_bounds__(256) void fc_kernel(
    const float* __restrict__ a5, const float* __restrict__ scale, const float* __restrict__ shift,
    const float* __restrict__ fcT, const float* __restrict__ fc_b, float* __restrict__ outp)
{
  __shared__ float f[1024];
  __shared__ float part[256];
  __shared__ float lg[128];
  const int b = blockIdx.x, t = threadIdx.x;
  for (int e=t; e<1024; e+=256){
    int c = e & 255, hw = e >> 8;
    float v = a5[b*1024 + e];
    f[c*4 + hw] = fmaf(v, scale[c], shift[c]);
  }
  __syncthreads();
  const int o = t & 127, half = t >> 7;
  float s = 0.f;
  if (o < 100){
    const float* fp = f + half*512;
    const float* wp = fcT + half*512*100 + o;
    for (int j=0;j<512;++j) s = fmaf(fp[j], wp[j*100], s);
  }
  part[t] = s; __syncthreads();
  if (t < 128){
    float logit = part[t] + part[t+128] + ((t<100)? fc_b[t] : 0.f);
    lg[t] = (t<100)? logit : -3.0e38f;
    if (t<100) outp[b*100 + t] = logit;
  }
  __syncthreads();
  if (t==0){
    float m = lg[0]; int mi = 0;
    for (int i=1;i<100;++i){ if (lg[i] > m){ m = lg[i]; mi = i; } }
    outp[25600 + b] = (float)mi;
  }
}

// ---------------- launch ----------------
extern "C" void kernel_launch(void* const* d_in, const int* in_sizes, int n_in,
                              void* d_out, int out_size, void* d_ws, size_t ws_size,
                              hipStream_t stream)
{
  (void)in_sizes; (void)n_in; (void)out_size;
  const float* x     = (const float*)d_in[0];
  const float* enc_w = (const float*)d_in[1];
  const float* enc_b = (const float*)d_in[2];
  const float* dec_w = (const float*)d_in[3];
  const float* dec_b = (const float*)d_in[4];
  const float* red_w = (const float*)d_in[5];
  const float* red_b = (const float*)d_in[6];
  const float* bn1_g = (const float*)d_in[7];  const float* bn1_b = (const float*)d_in[8];
  const float* c1w   = (const float*)d_in[9];  const float* c1b   = (const float*)d_in[10];
  const float* bn2_g = (const float*)d_in[11]; const float* bn2_b = (const float*)d_in[12];
  const float* c2w   = (const float*)d_in[13]; const float* c2b   = (const float*)d_in[14];
  const float* bn3_g = (const float*)d_in[15]; const float* bn3_b = (const float*)d_in[16];
  const float* c3w   = (const float*)d_in[17]; const float* c3b   = (const float*)d_in[18];
  const float* bn4_g = (const float*)d_in[19]; const float* bn4_b = (const float*)d_in[20];
  const float* c4w   = (const float*)d_in[21]; const float* c4b   = (const float*)d_in[22];
  const float* bn5_g = (const float*)d_in[23]; const float* bn5_b = (const float*)d_in[24];
  const float* c5w   = (const float*)d_in[25]; const float* c5b   = (const float*)d_in[26];
  const float* bnc_g = (const float*)d_in[27]; const float* bnc_b = (const float*)d_in[28];
  const float* fc_w  = (const float*)d_in[29]; const float* fc_b  = (const float*)d_in[30];
  const int*   kp    = (const int*)d_in[31];
  float* out = (float*)d_out;
  float* ws  = (float*)d_ws;

  // ---- workspace layout (floats) ----
  constexpr size_t OFF_ENCT = 0;                      // 6912 -> pad 7168
  constexpr size_t OFF_DECT = 7168;                   // 6912 -> pad 7168
  constexpr size_t OFF_REDT = 14336;                  // 16384
  constexpr size_t OFF_FCT  = OFF_REDT + 16384;       // 102400
  constexpr size_t OFF_WT1  = OFF_FCT + 102400;       // 55296
  constexpr size_t OFF_WT2  = OFF_WT1 + 55296;        // 110592
  constexpr size_t OFF_WT3  = OFF_WT2 + 110592;       // 184320
  constexpr size_t OFF_WT4  = OFF_WT3 + 184320;       // 276480
  constexpr size_t OFF_WT5  = OFF_WT4 + 276480;       // 442368
  constexpr size_t OFF_SS1  = OFF_WT5 + 442368;       // 128
  constexpr size_t OFF_SS2  = OFF_SS1 + 128;          // 192
  constexpr size_t OFF_SS3  = OFF_SS2 + 192;          // 256
  constexpr size_t OFF_SS4  = OFF_SS3 + 256;          // 320
  constexpr size_t OFF_SS5  = OFF_SS4 + 320;          // 384
  constexpr size_t OFF_SSC  = OFF_SS5 + 384;          // 512
  constexpr size_t OFF_PSUM = OFF_SSC + 512;          // 49152
  constexpr size_t OFF_PSQ  = OFF_PSUM + 49152;       // 49152
  constexpr size_t OFF_AUX  = OFF_PSQ + 49152;        // 900 -> pad 7936
  constexpr size_t OFF_A1   = OFF_AUX + 7936;         // 4816896
  constexpr size_t OFF_H0   = OFF_A1 + 4816896;       // 14745600 (h0T channel-major [64][230400])
  constexpr size_t OFF_A2   = OFF_H0;                 // overlays dead h0
  constexpr size_t OFF_A3   = OFF_A2 + 4718592;
  constexpr size_t OFF_A4   = OFF_A3 + 4096000;
  constexpr size_t OFF_A5   = OFF_A4 + 786432;
  constexpr size_t OFF_SVV  = OFF_H0 + 14745600;      // 32*230400 = 7372800 f32
  constexpr size_t OFF_SVI  = OFF_SVV + 7372800;      // 7372800 bytes = 1843200 floats
  constexpr size_t TOTALF   = OFF_SVI + 1843200;
  if (ws_size < TOTALF*sizeof(float)) return;

  float* encTg = ws + OFF_ENCT;
  float* decT = ws + OFF_DECT;  float* redT = ws + OFF_REDT;  float* fcT = ws + OFF_FCT;
  float* WT1 = ws + OFF_WT1; float* WT2 = ws + OFF_WT2; float* WT3 = ws + OFF_WT3;
  float* WT4 = ws + OFF_WT4; float* WT5 = ws + OFF_WT5;
  float* ss1 = ws + OFF_SS1; float* ss2 = ws + OFF_SS2; float* ss3 = ws + OFF_SS3;
  float* ss4 = ws + OFF_SS4; float* ss5 = ws + OFF_SS5; float* ssc = ws + OFF_SSC;
  float* psum = ws + OFF_PSUM; float* psq = ws + OFF_PSQ; float* auxp = ws + OFF_AUX;
  float* a1 = ws + OFF_A1; float* h0 = ws + OFF_H0;
  float* a2 = ws + OFF_A2; float* a3 = ws + OFF_A3; float* a4 = ws + OFF_A4; float* a5 = ws + OFF_A5;
  float* svv = ws + OFF_SVV;
  unsigned char* svi = (unsigned char*)(ws + OFF_SVI);

  const int G = 192;

  prep_all<<<982, 256, 0, stream>>>(enc_w, encTg, dec_w, decT, red_w, redT, fc_w, fcT,
                                    c1w, WT1, c2w, WT2, c3w, WT3, c4w, WT4, c5w, WT5);

  // stage A: A1 conv+topk+compact, A2 dec/aux, A3 red->h0T
  stage_a1<<<dim3(15,256), 512, 0, stream>>>(encTg, enc_b, x, kp, svv, svi);
  stage_a2<<<900, 256, 0, stream>>>(svv, svi, decT, dec_b, x, auxp);
  aux_reduce<<<1, 256, 0, stream>>>(auxp, out);
  stage_a3<<<450, 512, 0, stream>>>(svv, svi, redT, red_b, h0);

  // bn1 (channel-major) + conv1(+pool)
  bn_cm64<<<64, 256, 0, stream>>>(h0, psum, psq);
  bn_final<64><<<1, 256, 0, stream>>>(psum, psq, bn1_g, bn1_b, ss1, ss1+64, 1.f/230400.f, 1);
  conv3x3<64,96,30,30,true,true><<<dim3(14,256), 256, 0, stream>>>(h0, WT1, c1b, ss1, ss1+64, a1);

  // bn2 + conv2
  bn_partial<96,192><<<G, 192, 0, stream>>>(a1, psum, psq, 50176);
  bn_final<96><<<1, 256, 0, stream>>>(psum, psq, bn2_g, bn2_b, ss2, ss2+96, 1.f/50176.f, G);
  conv3x3<96,128,14,14,false,false><<<dim3(12,256), 256, 0, stream>>>(a1, WT2, c2b, ss2, ss2+96, a2);

  // bn3 + conv3
  bn_partial<128,256><<<G, 256, 0, stream>>>(a2, psum, psq, 36864);
  bn_final<128><<<1, 256, 0, stream>>>(psum, psq, bn3_g, bn3_b, ss3, ss3+128, 1.f/36864.f, G);
  conv3x3<128,160,12,12,false,false><<<dim3(10,256), 256, 0, stream>>>(a2, WT3, c3b, ss3, ss3+128, a3);

  // bn4 + conv4(+pool)
  bn_partial<160,320><<<G, 320, 0, stream>>>(a3, psum, psq, 25600);
  bn_final<160><<<1, 256, 0, stream>>>(psum, psq, bn4_g, bn4_b, ss4, ss4+160, 1.f/25600.f, G);
  conv3x3<160,192,10,10,true,false><<<dim3(4,256), 256, 0, stream>>>(a3, WT4, c4b, ss4, ss4+160, a4);

  // bn5 + conv5
  bn_partial<192,192><<<G, 192, 0, stream>>>(a4, psum, psq, 4096);
  bn_final<192><<<1, 256, 0, stream>>>(psum, psq, bn5_g, bn5_b, ss5, ss5+192, 1.f/4096.f, G);
  conv3x3<192,256,4,4,false,false><<<dim3(2,256), 256, 0, stream>>>(a4, WT5, c5b, ss5, ss5+192, a5);

  // bnc + fc + argmax
  bn_partial<256,256><<<G, 256, 0, stream>>>(a5, psum, psq, 1024);
  bn_final<256><<<1, 256, 0, stream>>>(psum, psq, bnc_g, bnc_b, ssc, ssc+256, 1.f/1024.f, G);
  fc_kernel<<<256, 256, 0, stream>>>(a5, ssc, ssc+256, fcT, fc_b, out);
}

// Round 5
// 1991.742 us; speedup vs baseline: 1.0637x; 1.0637x over previous
//
#include <hip/hip_runtime.h>

#define DEV_INLINE __device__ __forceinline__
typedef unsigned long long ull;

// ---------------- compile-time helpers ----------------
constexpr int roundup4(int v){ return (v+3)&~3; }
constexpr int lds_stride(int win){
  int s = roundup4(win);
  if (s % 16 == 0) s += 4;
  return s;
}

// ---------------- prep: all weight transposes in one launch ----------------
__global__ void prep_all(const float* __restrict__ enc_w, float* __restrict__ encTg,
                         const float* __restrict__ dec_w, float* __restrict__ decT,
                         const float* __restrict__ red_w, float* __restrict__ redT,
                         const float* __restrict__ fc_w,  float* __restrict__ fcT,
                         const float* __restrict__ c1w, float* __restrict__ WT1,
                         const float* __restrict__ c2w, float* __restrict__ WT2,
                         const float* __restrict__ c3w, float* __restrict__ WT3,
                         const float* __restrict__ c4w, float* __restrict__ WT4,
                         const float* __restrict__ c5w, float* __restrict__ WT5)
{
  const int b = blockIdx.x, t = threadIdx.x;
  auto t2 = [&](const float* A, float* AT, int R, int C, int base){
    int i = (b-base)*256 + t; if (i < R*C){ int r=i%R, c=i/R; AT[i] = A[r*C+c]; }
  };
  auto tw = [&](const float* W, float* WT, int O, int I, int base){
    int i = (b-base)*256 + t;
    if (i < O*I){ int o=i%O, ii=i/O;
      const float* s = W + (size_t)(o*I+ii)*9;
      #pragma unroll
      for (int kk=0;kk<9;++kk) WT[(kk*I+ii)*O+o] = s[kk]; }
  };
  if      (b < 27)  t2(enc_w, encTg, 256, 27, 0);
  else if (b < 54)  t2(dec_w, decT, 27, 256, 27);
  else if (b < 118) t2(red_w, redT, 64, 256, 54);
  else if (b < 518) t2(fc_w,  fcT, 100, 1024, 118);
  else if (b < 542) tw(c1w, WT1, 96, 64, 518);
  else if (b < 590) tw(c2w, WT2, 128, 96, 542);
  else if (b < 670) tw(c3w, WT3, 160, 128, 590);
  else if (b < 790) tw(c4w, WT4, 192, 160, 670);
  else              tw(c5w, WT5, 256, 192, 790);
}

// ---------------- A1: enc conv + early-exit topk + compact survivors ----------------
// grid (15, 256) = (oh-pair, b); 512 threads (8 waves) share one weight tile.
// __launch_bounds__(512,6): VGPR budget ~85 so the pair kernel (~55 live regs)
// does NOT spill (round-4's (512,8) forced budget 64 -> 32-reg + 2.1 GB scratch
// traffic, memory-bound). Runtime occupancy still 4 blocks/CU if VGPR<=64.
__global__ __launch_bounds__(512, 6) void stage_a1(
    const float* __restrict__ encTg, const float* __restrict__ enc_b,
    const float* __restrict__ x, const int* __restrict__ kp,
    float* __restrict__ svg_v, unsigned char* __restrict__ svg_i)
{
  __shared__ float4 encT4[27*64];          // 27648 B
  __shared__ float  rows[12*32];           // 1536 B: x rows oh0..oh0+3, [ci*4+r][32]
  __shared__ float  svf[60*33];            // 7920 B (stride 33: conflict-free col reads)
  __shared__ unsigned char svi[60*33];     // 1980 B

  const int t = threadIdx.x, bx = blockIdx.x, b = blockIdx.y;
  const int oh0 = 2*bx;
  const int k = __builtin_amdgcn_readfirstlane(*kp);
  const int wid = t>>6, lane = t&63;
  float* encT = (float*)encT4;

  for (int e=t; e<6912; e+=512) encT[e] = encTg[e];
  for (int e=t; e<384; e+=512){
    int ci = e/128, r = (e>>5)&3, xx = e&31;
    rows[(ci*4+r)*32+xx] = x[((b*3+ci)*32 + (oh0+r))*32 + xx];
  }
  for (int e=t; e<1980; e+=512){ svf[e]=0.f; svi[e]=0; }
  __syncthreads();

  const float4 eb = ((const float4*)enc_b)[lane];

  auto cnt4 = [&](unsigned c, unsigned u0, unsigned u1, unsigned u2, unsigned u3)->int{
    return __popcll(__ballot(u0>=c)) + __popcll(__ballot(u1>=c))
         + __popcll(__ballot(u2>=c)) + __popcll(__ballot(u3>=c));
  };
  auto compact = [&](float v0,float v1,float v2,float v3,
                     unsigned u0,unsigned u1,unsigned u2,unsigned u3,
                     unsigned th, int pi){
    bool k0=u0>=th, k1=u1>=th, k2=u2>=th, k3=u3>=th;
    ull B0=__ballot(k0), B1=__ballot(k1), B2=__ballot(k2), B3=__ballot(k3);
    ull below=(1ull<<lane)-1ull;
    int n0=__popcll(B0), n1=__popcll(B1), n2=__popcll(B2);
    int o0=__popcll(B0&below);
    int o1=n0+__popcll(B1&below);
    int o2=n0+n1+__popcll(B2&below);
    int o3=n0+n1+n2+__popcll(B3&below);
    float* sf = &svf[pi*33]; unsigned char* si = &svi[pi*33];
    if (k0&&o0<32){ sf[o0]=v0; si[o0]=(unsigned char)(4*lane+0); }
    if (k1&&o1<32){ sf[o1]=v1; si[o1]=(unsigned char)(4*lane+1); }
    if (k2&&o2<32){ sf[o2]=v2; si[o2]=(unsigned char)(4*lane+2); }
    if (k3&&o3<32){ sf[o3]=v3; si[o3]=(unsigned char)(4*lane+3); }
  };

  for (int pp = wid; pp < 30; pp += 8){
    const int rr = pp/15, j = pp - rr*15;
    const int ow0 = 2*j;
    const int pi0 = rr*30 + ow0;

    float a0=eb.x,a1=eb.y,a2=eb.z,a3=eb.w;
    float c0=eb.x,c1=eb.y,c2=eb.z,c3=eb.w;
    #pragma unroll
    for (int ci=0; ci<3; ++ci)
      #pragma unroll
      for (int i=0;i<3;++i){
        const int rbase = (ci*4 + rr + i)*32;
        float p0 = rows[rbase+ow0+0], p1 = rows[rbase+ow0+1];
        float p2 = rows[rbase+ow0+2], p3 = rows[rbase+ow0+3];
        float4 w0 = encT4[(ci*9+i*3+0)*64 + lane];
        float4 w1 = encT4[(ci*9+i*3+1)*64 + lane];
        float4 w2 = encT4[(ci*9+i*3+2)*64 + lane];
        a0=fmaf(w0.x,p0,a0); a1=fmaf(w0.y,p0,a1); a2=fmaf(w0.z,p0,a2); a3=fmaf(w0.w,p0,a3);
        c0=fmaf(w0.x,p1,c0); c1=fmaf(w0.y,p1,c1); c2=fmaf(w0.z,p1,c2); c3=fmaf(w0.w,p1,c3);
        a0=fmaf(w1.x,p1,a0); a1=fmaf(w1.y,p1,a1); a2=fmaf(w1.z,p1,a2); a3=fmaf(w1.w,p1,a3);
        c0=fmaf(w1.x,p2,c0); c1=fmaf(w1.y,p2,c1); c2=fmaf(w1.z,p2,c2); c3=fmaf(w1.w,p2,c3);
        a0=fmaf(w2.x,p2,a0); a1=fmaf(w2.y,p2,a1); a2=fmaf(w2.z,p2,a2); a3=fmaf(w2.w,p2,a3);
        c0=fmaf(w2.x,p3,c0); c1=fmaf(w2.y,p3,c1); c2=fmaf(w2.z,p3,c2); c3=fmaf(w2.w,p3,c3);
      }

    unsigned A0=__float_as_uint(a0)&0x7fffffffu, A1=__float_as_uint(a1)&0x7fffffffu;
    unsigned A2=__float_as_uint(a2)&0x7fffffffu, A3=__float_as_uint(a3)&0x7fffffffu;
    unsigned C0=__float_as_uint(c0)&0x7fffffffu, C1=__float_as_uint(c1)&0x7fffffffu;
    unsigned C2=__float_as_uint(c2)&0x7fffffffu, C3=__float_as_uint(c3)&0x7fffffffu;

    // dual exact kth-largest-|v|, radix-2 with EARLY EXIT:
    // if exactly k values >= th, {a>=th} == {a>=kth} (mask-exact) -> stop.
    unsigned thA=0, thB=0;
    int dA=0, dB=0;
    for (int bit=30; bit>=0; --bit){
      if (!dA){
        unsigned c = thA | (1u<<bit);
        int n = cnt4(c,A0,A1,A2,A3);
        if (n>=k) thA=c;
        if (n==k) dA=1;
      }
      if (!dB){
        unsigned c = thB | (1u<<bit);
        int n = cnt4(c,C0,C1,C2,C3);
        if (n>=k) thB=c;
        if (n==k) dB=1;
      }
      if (dA & dB) break;
    }

    compact(a0,a1,a2,a3, A0,A1,A2,A3, thA, pi0);
    compact(c0,c1,c2,c3, C0,C1,C2,C3, thB, pi0+1);
  }
  __syncthreads();

  // coalesced store: global layout [slot][pos]
  const size_t gbase = (size_t)b*900 + (size_t)bx*60;
  for (int e=t; e<1920; e+=512){
    int jj = e/60, pi = e - jj*60;
    svg_v[(size_t)jj*230400 + gbase + pi] = svf[pi*33+jj];
    svg_i[(size_t)jj*230400 + gbase + pi] = svi[pi*33+jj];
  }
}

// ---------------- A2: dec + sigmoid + aux (position-per-lane, decT in LDS) ----------------
__global__ __launch_bounds__(256, 5) void stage_a2(
    const float* __restrict__ svg_v, const unsigned char* __restrict__ svg_i,
    const float* __restrict__ decT, const float* __restrict__ dec_b,
    const float* __restrict__ x, float* __restrict__ auxp)
{
  __shared__ float decl[6912];   // [idx][o], stride 27
  __shared__ float redbuf[256];
  const int t = threadIdx.x;
  for (int e=t; e<6912; e+=256) decl[e] = decT[e];
  __syncthreads();

  const int pos = blockIdx.x*256 + t;
  const int b = pos/900, rem = pos - b*900;
  const int oh = rem/30, ow = rem - (rem/30)*30;

  float d[27];
  #pragma unroll
  for (int o=0;o<27;++o) d[o] = dec_b[o];
  for (int jj=0; jj<32; ++jj){
    float v  = svg_v[(size_t)jj*230400 + pos];
    int  idx = (int)svg_i[(size_t)jj*230400 + pos];
    const float* wr = decl + idx*27;
    #pragma unroll
    for (int o=0;o<27;++o) d[o] = fmaf(v, wr[o], d[o]);
  }
  float acc = 0.f;
  #pragma unroll
  for (int o=0;o<27;++o){
    int ci = o/9, r2 = (o - ci*9)/3, c2 = o%3;
    float tg = x[((b*3+ci)*32 + (oh+r2))*32 + (ow+c2)];
    float dv = 1.f/(1.f + __expf(-d[o]));
    float df = tg - dv;
    acc = fmaf(df, df, acc);
  }
  redbuf[t]=acc; __syncthreads();
  for (int off=128; off; off>>=1){ if (t<off) redbuf[t]+=redbuf[t+off]; __syncthreads(); }
  if (t==0) auxp[blockIdx.x] = redbuf[0];
}

__global__ void aux_reduce(const float* __restrict__ p, float* __restrict__ outp){
  __shared__ float s[256];
  int t = threadIdx.x; float a=0.f;
  for (int i=t; i<900; i+=256) a += p[i];
  s[t]=a; __syncthreads();
  for (int off=128; off; off>>=1){ if (t<off) s[t]+=s[t+off]; __syncthreads(); }
  if (t==0) outp[25856] = s[0] / 6220800.0f;
}

// ---------------- A3: red -> h0 channel-major (position-per-lane, redT in LDS) ----------------
__global__ __launch_bounds__(512, 4) void stage_a3(
    const float* __restrict__ svg_v, const unsigned char* __restrict__ svg_i,
    const float* __restrict__ redT, const float* __restrict__ red_b,
    float* __restrict__ h0T)
{
  __shared__ float redl[256*65];   // [idx][o] stride 65 -> bank (idx+o)%32
  const int t = threadIdx.x;
  for (int e=t; e<16384; e+=512) redl[(e>>6)*65 + (e&63)] = redT[e];
  __syncthreads();

  const size_t pos = (size_t)blockIdx.x*512 + t;
  float v[32]; int a[32];
  #pragma unroll
  for (int jj=0;jj<32;++jj) v[jj] = svg_v[(size_t)jj*230400 + pos];
  #pragma unroll
  for (int jj=0;jj<32;++jj) a[jj] = (int)svg_i[(size_t)jj*230400 + pos]*65;

  #pragma unroll 2
  for (int o=0;o<64;++o){
    float acc0 = red_b[o], acc1 = 0.f;
    #pragma unroll
    for (int jj=0;jj<32;jj+=2){
      acc0 = fmaf(v[jj],   redl[a[jj]+o],   acc0);
      acc1 = fmaf(v[jj+1], redl[a[jj+1]+o], acc1);
    }
    h0T[(size_t)o*230400 + pos] = acc0 + acc1;
  }
}

// ---------------- BN stats ----------------
__global__ void bn_cm64(const float* __restrict__ h0T, float* __restrict__ psum,
                        float* __restrict__ psq){
  __shared__ float ls[256], lq[256];
  const int t = threadIdx.x;
  const float4* p = (const float4*)(h0T + (size_t)blockIdx.x*230400);
  float s=0.f, q=0.f;
  for (int i=t; i<57600; i+=256){
    float4 f = p[i];
    s += f.x+f.y+f.z+f.w;
    q = fmaf(f.x,f.x,q); q = fmaf(f.y,f.y,q); q = fmaf(f.z,f.z,q); q = fmaf(f.w,f.w,q);
  }
  ls[t]=s; lq[t]=q; __syncthreads();
  for (int off=128; off; off>>=1){
    if (t<off){ ls[t]+=ls[t+off]; lq[t]+=lq[t+off]; } __syncthreads();
  }
  if (t==0){ psum[blockIdx.x]=ls[0]; psq[blockIdx.x]=lq[0]; }
}

template<int C, int BD>
__global__ void bn_partial(const float* __restrict__ in, float* __restrict__ psum,
                           float* __restrict__ psq, int npos){
  constexpr int GPB = BD / C;
  const int t = threadIdx.x;
  const int c = t % C, g = t / C;
  float s=0.f, q=0.f;
  for (int i = blockIdx.x*GPB + g; i < npos; i += gridDim.x*GPB){
    float v = in[i*C + c];
    s += v; q = fmaf(v, v, q);
  }
  __shared__ float ls[BD], lq[BD];
  ls[t]=s; lq[t]=q; __syncthreads();
  for (int off=BD/2; off>=C; off>>=1){
    if (t<off){ ls[t]+=ls[t+off]; lq[t]+=lq[t+off]; }
    __syncthreads();
  }
  if (t<C){ psum[blockIdx.x*C+t]=ls[t]; psq[blockIdx.x*C+t]=lq[t]; }
}

template<int C>
__global__ void bn_final(const float* __restrict__ ps, const float* __restrict__ pq,
                         const float* __restrict__ g, const float* __restrict__ b2,
                         float* __restrict__ sc, float* __restrict__ sh, float inv_n, int G){
  int t = threadIdx.x;
  if (t >= C) return;
  float s=0.f, q=0.f;
  for (int i=0;i<G;++i){ s += ps[i*C+t]; q += pq[i*C+t]; }
  float m = s*inv_n;
  float v = fmaf(q, inv_n, -m*m);
  float rs = rsqrtf(v + 1e-5f);
  float scale = g[t]*rs;
  sc[t] = scale;
  sh[t] = fmaf(-m, scale, b2[t]);
}

// ---------------- generic 3x3 valid conv, fused BN+ReLU in, optional maxpool ----------------
template<int CIN,int COUT,int HIN,int WIN,bool POOL,int NPOS>
DEV_INLINE void conv_compute(const float* lds, const float* __restrict__ wt,
                             const float* __restrict__ bias, float* __restrict__ out,
                             int b, int orow, int iw0, int co, bool cok)
{
  constexpr int S = lds_stride(WIN);
  constexpr int NROWS = POOL ? 4 : 3;
  constexpr int HC = HIN-2, WC = WIN-2;
  constexpr int IVL = roundup4(NPOS+2);
  float acc0[NPOS], acc1[POOL?NPOS:1];
  const float bv = bias[co];
  #pragma unroll
  for (int p=0;p<NPOS;++p) acc0[p]=bv;
  if (POOL){
    #pragma unroll
    for (int p=0;p<NPOS;++p) acc1[p]=bv;
  }
  for (int ci=0; ci<CIN; ++ci){
    #pragma unroll
    for (int r=0;r<NROWS;++r){
      float iv[IVL];
      const float4* rp = (const float4*)(lds + (r*CIN+ci)*S + iw0);
      #pragma unroll
      for (int q=0;q<IVL/4;++q){
        float4 f = rp[q];
        iv[4*q+0]=f.x; iv[4*q+1]=f.y; iv[4*q+2]=f.z; iv[4*q+3]=f.w;
      }
      #pragma unroll
      for (int kw=0;kw<3;++kw){
        if (!POOL || r < 3){
          float w = wt[((r*3+kw)*CIN+ci)*COUT + co];
          #pragma unroll
          for (int p=0;p<NPOS;++p) acc0[p] = fmaf(iv[p+kw], w, acc0[p]);
        }
        if (POOL && r >= 1){
          float w = wt[(((r-1)*3+kw)*CIN+ci)*COUT + co];
          #pragma unroll
          for (int p=0;p<NPOS;++p) acc1[p] = fmaf(iv[p+kw], w, acc1[p]);
        }
      }
    }
  }
  if (!cok) return;
  if (POOL){
    constexpr int HP=HC/2, WP=WC/2;
    #pragma unroll
    for (int q=0;q<NPOS/2;++q){
      float m = fmaxf(fmaxf(acc0[2*q],acc0[2*q+1]), fmaxf(acc1[2*q],acc1[2*q+1]));
      out[((b*HP + orow)*WP + (iw0>>1) + q)*COUT + co] = m;
    }
  } else {
    #pragma unroll
    for (int p=0;p<NPOS;++p)
      out[((b*HC + orow)*WC + iw0 + p)*COUT + co] = acc0[p];
  }
}

template<int CIN,int COUT,int HIN,int WIN,bool POOL,bool CMIN>
__global__ __launch_bounds__(256) void conv3x3(
    const float* __restrict__ in, const float* __restrict__ wt,
    const float* __restrict__ bias, const float* __restrict__ scale,
    const float* __restrict__ shift, float* __restrict__ out)
{
  constexpr int WC = WIN-2;
  constexpr int NROWS = POOL ? 4 : 3;
  constexpr int S = lds_stride(WIN);
  constexpr size_t NPIX = (size_t)256*HIN*WIN;
  __shared__ float4 lds4[(NROWS*CIN*S)/4];
  float* lds = (float*)lds4;

  const int b = blockIdx.y, orow = blockIdx.x;
  const int ih0 = POOL ? 2*orow : orow;
  const float* src = in + ((long)(b*HIN + ih0))*WIN*CIN;
  for (int e = threadIdx.x; e < NROWS*WIN*CIN; e += 256){
    int c, iw, r; float v;
    if constexpr (CMIN){
      iw = e % WIN; int rest = e / WIN; c = rest % CIN; r = rest / CIN;
      v = in[(size_t)c*NPIX + ((size_t)b*HIN + ih0 + r)*WIN + iw];
    } else {
      c = e % CIN; int rest = e / CIN; iw = rest % WIN; r = rest / WIN;
      v = src[e];
    }
    v = fmaxf(fmaf(v, scale[c], shift[c]), 0.f);
    lds[(r*CIN + c)*S + iw] = v;
  }
  __syncthreads();

  const int wid = threadIdx.x>>6, lane = threadIdx.x&63;
  constexpr int NCHUNK = (COUT+63)/64;
  constexpr int NSTRIP = (NCHUNK<=2 && WC>4) ? 2 : 1;
  constexpr int NPOS0  = (NSTRIP==2) ? ((WC/2+3)&~3) : WC;
  if (wid >= NCHUNK*NSTRIP) return;
  int chunk, strip;
  if (NSTRIP==2){ chunk = wid & 1; strip = wid >> 1; } else { chunk = wid; strip = 0; }
  const int co = chunk*64 + lane;
  const bool cok = co < COUT;
  const int coc = cok ? co : (COUT-1);
  if (strip==0){
    conv_compute<CIN,COUT,HIN,WIN,POOL,NPOS0>(lds, wt, bias, out, b, orow, 0, coc, cok);
  } else {
    if constexpr (NSTRIP==2){
      constexpr int NPOS1 = WC - NPOS0;
      conv_compute<CIN,COUT,HIN,WIN,POOL,NPOS1>(lds, wt, bias, out, b, orow, NPOS0, coc, cok);
    }
  }
}

// ---------------- final: bnc + FC + argmax ----------------
__global__ __launch_bounds__(256) void fc_kernel(
    const float* __restrict__ a5, const float* __restrict__ scale, const float* __restrict__ shift,
    const float* __restrict__ fcT, const float* __restrict__ fc_b, float* __restrict__ outp)
{
  __shared__ float f[1024];
  __shared__ float part[256];
  __shared__ float lg[128];
  const int b = blockIdx.x, t = threadIdx.x;
  for (int e=t; e<1024; e+=256){
    int c = e & 255, hw = e >> 8;
    float v = a5[b*1024 + e];
    f[c*4 + hw] = fmaf(v, scale[c], shift[c]);
  }
  __syncthreads();
  const int o = t & 127, half = t >> 7;
  float s = 0.f;
  if (o < 100){
    const float* fp = f + half*512;
    const float* wp = fcT + half*512*100 + o;
    for (int j=0;j<512;++j) s = fmaf(fp[j], wp[j*100], s);
  }
  part[t] = s; __syncthreads();
  if (t < 128){
    float logit = part[t] + part[t+128] + ((t<100)? fc_b[t] : 0.f);
    lg[t] = (t<100)? logit : -3.0e38f;
    if (t<100) outp[b*100 + t] = logit;
  }
  __syncthreads();
  if (t==0){
    float m = lg[0]; int mi = 0;
    for (int i=1;i<100;++i){ if (lg[i] > m){ m = lg[i]; mi = i; } }
    outp[25600 + b] = (float)mi;
  }
}

// ---------------- launch ----------------
extern "C" void kernel_launch(void* const* d_in, const int* in_sizes, int n_in,
                              void* d_out, int out_size, void* d_ws, size_t ws_size,
                              hipStream_t stream)
{
  (void)in_sizes; (void)n_in; (void)out_size;
  const float* x     = (const float*)d_in[0];
  const float* enc_w = (const float*)d_in[1];
  const float* enc_b = (const float*)d_in[2];
  const float* dec_w = (const float*)d_in[3];
  const float* dec_b = (const float*)d_in[4];
  const float* red_w = (const float*)d_in[5];
  const float* red_b = (const float*)d_in[6];
  const float* bn1_g = (const float*)d_in[7];  const float* bn1_b = (const float*)d_in[8];
  const float* c1w   = (const float*)d_in[9];  const float* c1b   = (const float*)d_in[10];
  const float* bn2_g = (const float*)d_in[11]; const float* bn2_b = (const float*)d_in[12];
  const float* c2w   = (const float*)d_in[13]; const float* c2b   = (const float*)d_in[14];
  const float* bn3_g = (const float*)d_in[15]; const float* bn3_b = (const float*)d_in[16];
  const float* c3w   = (const float*)d_in[17]; const float* c3b   = (const float*)d_in[18];
  const float* bn4_g = (const float*)d_in[19]; const float* bn4_b = (const float*)d_in[20];
  const float* c4w   = (const float*)d_in[21]; const float* c4b   = (const float*)d_in[22];
  const float* bn5_g = (const float*)d_in[23]; const float* bn5_b = (const float*)d_in[24];
  const float* c5w   = (const float*)d_in[25]; const float* c5b   = (const float*)d_in[26];
  const float* bnc_g = (const float*)d_in[27]; const float* bnc_b = (const float*)d_in[28];
  const float* fc_w  = (const float*)d_in[29]; const float* fc_b  = (const float*)d_in[30];
  const int*   kp    = (const int*)d_in[31];
  float* out = (float*)d_out;
  float* ws  = (float*)d_ws;

  // ---- workspace layout (floats) ----
  constexpr size_t OFF_ENCT = 0;
  constexpr size_t OFF_DECT = 7168;
  constexpr size_t OFF_REDT = 14336;
  constexpr size_t OFF_FCT  = OFF_REDT + 16384;
  constexpr size_t OFF_WT1  = OFF_FCT + 102400;
  constexpr size_t OFF_WT2  = OFF_WT1 + 55296;
  constexpr size_t OFF_WT3  = OFF_WT2 + 110592;
  constexpr size_t OFF_WT4  = OFF_WT3 + 184320;
  constexpr size_t OFF_WT5  = OFF_WT4 + 276480;
  constexpr size_t OFF_SS1  = OFF_WT5 + 442368;
  constexpr size_t OFF_SS2  = OFF_SS1 + 128;
  constexpr size_t OFF_SS3  = OFF_SS2 + 192;
  constexpr size_t OFF_SS4  = OFF_SS3 + 256;
  constexpr size_t OFF_SS5  = OFF_SS4 + 320;
  constexpr size_t OFF_SSC  = OFF_SS5 + 384;
  constexpr size_t OFF_PSUM = OFF_SSC + 512;
  constexpr size_t OFF_PSQ  = OFF_PSUM + 49152;
  constexpr size_t OFF_AUX  = OFF_PSQ + 49152;
  constexpr size_t OFF_A1   = OFF_AUX + 7936;
  constexpr size_t OFF_H0   = OFF_A1 + 4816896;       // h0T channel-major [64][230400]
  constexpr size_t OFF_A2   = OFF_H0;                 // overlays dead h0
  constexpr size_t OFF_A3   = OFF_A2 + 4718592;
  constexpr size_t OFF_A4   = OFF_A3 + 4096000;
  constexpr size_t OFF_A5   = OFF_A4 + 786432;
  constexpr size_t OFF_SVV  = OFF_H0 + 14745600;      // 32*230400
  constexpr size_t OFF_SVI  = OFF_SVV + 7372800;      // bytes region
  constexpr size_t TOTALF   = OFF_SVI + 1843200;
  if (ws_size < TOTALF*sizeof(float)) return;

  float* encTg = ws + OFF_ENCT;
  float* decT = ws + OFF_DECT;  float* redT = ws + OFF_REDT;  float* fcT = ws + OFF_FCT;
  float* WT1 = ws + OFF_WT1; float* WT2 = ws + OFF_WT2; float* WT3 = ws + OFF_WT3;
  float* WT4 = ws + OFF_WT4; float* WT5 = ws + OFF_WT5;
  float* ss1 = ws + OFF_SS1; float* ss2 = ws + OFF_SS2; float* ss3 = ws + OFF_SS3;
  float* ss4 = ws + OFF_SS4; float* ss5 = ws + OFF_SS5; float* ssc = ws + OFF_SSC;
  float* psum = ws + OFF_PSUM; float* psq = ws + OFF_PSQ; float* auxp = ws + OFF_AUX;
  float* a1 = ws + OFF_A1; float* h0 = ws + OFF_H0;
  float* a2 = ws + OFF_A2; float* a3 = ws + OFF_A3; float* a4 = ws + OFF_A4; float* a5 = ws + OFF_A5;
  float* svv = ws + OFF_SVV;
  unsigned char* svi = (unsigned char*)(ws + OFF_SVI);

  const int G = 192;

  prep_all<<<982, 256, 0, stream>>>(enc_w, encTg, dec_w, decT, red_w, redT, fc_w, fcT,
                                    c1w, WT1, c2w, WT2, c3w, WT3, c4w, WT4, c5w, WT5);

  // stage A: A1 conv+topk+compact, A2 dec/aux, A3 red->h0T
  stage_a1<<<dim3(15,256), 512, 0, stream>>>(encTg, enc_b, x, kp, svv, svi);
  stage_a2<<<900, 256, 0, stream>>>(svv, svi, decT, dec_b, x, auxp);
  aux_reduce<<<1, 256, 0, stream>>>(auxp, out);
  stage_a3<<<450, 512, 0, stream>>>(svv, svi, redT, red_b, h0);

  // bn1 (channel-major) + conv1(+pool)
  bn_cm64<<<64, 256, 0, stream>>>(h0, psum, psq);
  bn_final<64><<<1, 256, 0, stream>>>(psum, psq, bn1_g, bn1_b, ss1, ss1+64, 1.f/230400.f, 1);
  conv3x3<64,96,30,30,true,true><<<dim3(14,256), 256, 0, stream>>>(h0, WT1, c1b, ss1, ss1+64, a1);

  // bn2 + conv2
  bn_partial<96,192><<<G, 192, 0, stream>>>(a1, psum, psq, 50176);
  bn_final<96><<<1, 256, 0, stream>>>(psum, psq, bn2_g, bn2_b, ss2, ss2+96, 1.f/50176.f, G);
  conv3x3<96,128,14,14,false,false><<<dim3(12,256), 256, 0, stream>>>(a1, WT2, c2b, ss2, ss2+96, a2);

  // bn3 + conv3
  bn_partial<128,256><<<G, 256, 0, stream>>>(a2, psum, psq, 36864);
  bn_final<128><<<1, 256, 0, stream>>>(psum, psq, bn3_g, bn3_b, ss3, ss3+128, 1.f/36864.f, G);
  conv3x3<128,160,12,12,false,false><<<dim3(10,256), 256, 0, stream>>>(a2, WT3, c3b, ss3, ss3+128, a3);

  // bn4 + conv4(+pool)
  bn_partial<160,320><<<G, 320, 0, stream>>>(a3, psum, psq, 25600);
  bn_final<160><<<1, 256, 0, stream>>>(psum, psq, bn4_g, bn4_b, ss4, ss4+160, 1.f/25600.f, G);
  conv3x3<160,192,10,10,true,false><<<dim3(4,256), 256, 0, stream>>>(a3, WT4, c4b, ss4, ss4+160, a4);

  // bn5 + conv5
  bn_partial<192,192><<<G, 192, 0, stream>>>(a4, psum, psq, 4096);
  bn_final<192><<<1, 256, 0, stream>>>(psum, psq, bn5_g, bn5_b, ss5, ss5+192, 1.f/4096.f, G);
  conv3x3<192,256,4,4,false,false><<<dim3(2,256), 256, 0, stream>>>(a4, WT5, c5b, ss5, ss5+192, a5);

  // bnc + fc + argmax
  bn_partial<256,256><<<G, 256, 0, stream>>>(a5, psum, psq, 1024);
  bn_final<256><<<1, 256, 0, stream>>>(psum, psq, bnc_g, bnc_b, ssc, ssc+256, 1.f/1024.f, G);
  fc_kernel<<<256, 256, 0, stream>>>(a5, ssc, ssc+256, fcT, fc_b, out);
}

// Round 6
// 1884.095 us; speedup vs baseline: 1.1244x; 1.0571x over previous
//
#include <hip/hip_runtime.h>

#define DEV_INLINE __device__ __forceinline__
typedef unsigned long long ull;

// ---------------- compile-time helpers ----------------
constexpr int roundup4(int v){ return (v+3)&~3; }
constexpr int lds_stride(int win){
  int s = roundup4(win);
  if (s % 16 == 0) s += 4;
  return s;
}

// ---------------- prep: all weight transposes in one launch ----------------
__global__ void prep_all(const float* __restrict__ enc_w, float* __restrict__ encTg,
                         const float* __restrict__ dec_w, float* __restrict__ decT,
                         const float* __restrict__ red_w, float* __restrict__ redT,
                         const float* __restrict__ fc_w,  float* __restrict__ fcT,
                         const float* __restrict__ c1w, float* __restrict__ WT1,
                         const float* __restrict__ c2w, float* __restrict__ WT2,
                         const float* __restrict__ c3w, float* __restrict__ WT3,
                         const float* __restrict__ c4w, float* __restrict__ WT4,
                         const float* __restrict__ c5w, float* __restrict__ WT5)
{
  const int b = blockIdx.x, t = threadIdx.x;
  auto t2 = [&](const float* A, float* AT, int R, int C, int base){
    int i = (b-base)*256 + t; if (i < R*C){ int r=i%R, c=i/R; AT[i] = A[r*C+c]; }
  };
  auto tw = [&](const float* W, float* WT, int O, int I, int base){
    int i = (b-base)*256 + t;
    if (i < O*I){ int o=i%O, ii=i/O;
      const float* s = W + (size_t)(o*I+ii)*9;
      #pragma unroll
      for (int kk=0;kk<9;++kk) WT[(kk*I+ii)*O+o] = s[kk]; }
  };
  if      (b < 27)  t2(enc_w, encTg, 256, 27, 0);
  else if (b < 54)  t2(dec_w, decT, 27, 256, 27);
  else if (b < 118) t2(red_w, redT, 64, 256, 54);
  else if (b < 518) t2(fc_w,  fcT, 100, 1024, 118);
  else if (b < 542) tw(c1w, WT1, 96, 64, 518);
  else if (b < 590) tw(c2w, WT2, 128, 96, 542);
  else if (b < 670) tw(c3w, WT3, 160, 128, 590);
  else if (b < 790) tw(c4w, WT4, 192, 160, 670);
  else              tw(c5w, WT5, 256, 192, 790);
}

// ---------------- A1: enc conv + early-exit topk + compact survivors ----------------
// grid (15, 256); 512 threads (8 waves) share one weight tile.
// NOTE (r4/r5 measured): 2nd __launch_bounds__ arg behaves as CUDA-style
// min-BLOCKS-per-CU on this toolchain: (512,8)->VGPR 32, (512,6)->VGPR 40
// (both = 512/(arg*2)), causing massive scratch spill (1.6-2.1 GB traffic).
// (512,2) -> budget >=128 regs: kernel needs ~60 -> no spill; LDS (39.4 KB)
// still allows 4 blocks/CU at runtime.
__global__ __launch_bounds__(512, 2) void stage_a1(
    const float* __restrict__ encTg, const float* __restrict__ enc_b,
    const float* __restrict__ x, const int* __restrict__ kp,
    float* __restrict__ svg_v, unsigned char* __restrict__ svg_i)
{
  __shared__ float4 encT4[27*64];          // 27648 B
  __shared__ float  rows[12*32];           // 1536 B: x rows oh0..oh0+3, [ci*4+r][32]
  __shared__ float  svf[60*33];            // 7920 B (stride 33: conflict-free col reads)
  __shared__ unsigned char svi[60*33];     // 1980 B

  const int t = threadIdx.x, bx = blockIdx.x, b = blockIdx.y;
  const int oh0 = 2*bx;
  const int k = __builtin_amdgcn_readfirstlane(*kp);
  const int wid = t>>6, lane = t&63;
  float* encT = (float*)encT4;

  for (int e=t; e<6912; e+=512) encT[e] = encTg[e];
  for (int e=t; e<384; e+=512){
    int ci = e/128, r = (e>>5)&3, xx = e&31;
    rows[(ci*4+r)*32+xx] = x[((b*3+ci)*32 + (oh0+r))*32 + xx];
  }
  for (int e=t; e<1980; e+=512){ svf[e]=0.f; svi[e]=0; }
  __syncthreads();

  const float4 eb = ((const float4*)enc_b)[lane];

  auto cnt4 = [&](unsigned c, unsigned u0, unsigned u1, unsigned u2, unsigned u3)->int{
    return __popcll(__ballot(u0>=c)) + __popcll(__ballot(u1>=c))
         + __popcll(__ballot(u2>=c)) + __popcll(__ballot(u3>=c));
  };
  auto compact = [&](float v0,float v1,float v2,float v3,
                     unsigned u0,unsigned u1,unsigned u2,unsigned u3,
                     unsigned th, int pi){
    bool k0=u0>=th, k1=u1>=th, k2=u2>=th, k3=u3>=th;
    ull B0=__ballot(k0), B1=__ballot(k1), B2=__ballot(k2), B3=__ballot(k3);
    ull below=(1ull<<lane)-1ull;
    int n0=__popcll(B0), n1=__popcll(B1), n2=__popcll(B2);
    int o0=__popcll(B0&below);
    int o1=n0+__popcll(B1&below);
    int o2=n0+n1+__popcll(B2&below);
    int o3=n0+n1+n2+__popcll(B3&below);
    float* sf = &svf[pi*33]; unsigned char* si = &svi[pi*33];
    if (k0&&o0<32){ sf[o0]=v0; si[o0]=(unsigned char)(4*lane+0); }
    if (k1&&o1<32){ sf[o1]=v1; si[o1]=(unsigned char)(4*lane+1); }
    if (k2&&o2<32){ sf[o2]=v2; si[o2]=(unsigned char)(4*lane+2); }
    if (k3&&o3<32){ sf[o3]=v3; si[o3]=(unsigned char)(4*lane+3); }
  };

  for (int pp = wid; pp < 30; pp += 8){
    const int rr = pp/15, j = pp - rr*15;
    const int ow0 = 2*j;
    const int pi0 = rr*30 + ow0;

    float a0=eb.x,a1=eb.y,a2=eb.z,a3=eb.w;
    float c0=eb.x,c1=eb.y,c2=eb.z,c3=eb.w;
    #pragma unroll
    for (int ci=0; ci<3; ++ci)
      #pragma unroll
      for (int i=0;i<3;++i){
        const int rbase = (ci*4 + rr + i)*32;
        float p0 = rows[rbase+ow0+0], p1 = rows[rbase+ow0+1];
        float p2 = rows[rbase+ow0+2], p3 = rows[rbase+ow0+3];
        float4 w0 = encT4[(ci*9+i*3+0)*64 + lane];
        float4 w1 = encT4[(ci*9+i*3+1)*64 + lane];
        float4 w2 = encT4[(ci*9+i*3+2)*64 + lane];
        a0=fmaf(w0.x,p0,a0); a1=fmaf(w0.y,p0,a1); a2=fmaf(w0.z,p0,a2); a3=fmaf(w0.w,p0,a3);
        c0=fmaf(w0.x,p1,c0); c1=fmaf(w0.y,p1,c1); c2=fmaf(w0.z,p1,c2); c3=fmaf(w0.w,p1,c3);
        a0=fmaf(w1.x,p1,a0); a1=fmaf(w1.y,p1,a1); a2=fmaf(w1.z,p1,a2); a3=fmaf(w1.w,p1,a3);
        c0=fmaf(w1.x,p2,c0); c1=fmaf(w1.y,p2,c1); c2=fmaf(w1.z,p2,c2); c3=fmaf(w1.w,p2,c3);
        a0=fmaf(w2.x,p2,a0); a1=fmaf(w2.y,p2,a1); a2=fmaf(w2.z,p2,a2); a3=fmaf(w2.w,p2,a3);
        c0=fmaf(w2.x,p3,c0); c1=fmaf(w2.y,p3,c1); c2=fmaf(w2.z,p3,c2); c3=fmaf(w2.w,p3,c3);
      }

    unsigned A0=__float_as_uint(a0)&0x7fffffffu, A1=__float_as_uint(a1)&0x7fffffffu;
    unsigned A2=__float_as_uint(a2)&0x7fffffffu, A3=__float_as_uint(a3)&0x7fffffffu;
    unsigned C0=__float_as_uint(c0)&0x7fffffffu, C1=__float_as_uint(c1)&0x7fffffffu;
    unsigned C2=__float_as_uint(c2)&0x7fffffffu, C3=__float_as_uint(c3)&0x7fffffffu;

    // dual exact kth-largest-|v|, radix-2 with EARLY EXIT:
    // if exactly k values >= th, {a>=th} == {a>=kth} (mask-exact) -> stop.
    unsigned thA=0, thB=0;
    int dA=0, dB=0;
    for (int bit=30; bit>=0; --bit){
      if (!dA){
        unsigned c = thA | (1u<<bit);
        int n = cnt4(c,A0,A1,A2,A3);
        if (n>=k) thA=c;
        if (n==k) dA=1;
      }
      if (!dB){
        unsigned c = thB | (1u<<bit);
        int n = cnt4(c,C0,C1,C2,C3);
        if (n>=k) thB=c;
        if (n==k) dB=1;
      }
      if (dA & dB) break;
    }

    compact(a0,a1,a2,a3, A0,A1,A2,A3, thA, pi0);
    compact(c0,c1,c2,c3, C0,C1,C2,C3, thB, pi0+1);
  }
  __syncthreads();

  // coalesced store: global layout [slot][pos]
  const size_t gbase = (size_t)b*900 + (size_t)bx*60;
  for (int e=t; e<1920; e+=512){
    int jj = e/60, pi = e - jj*60;
    svg_v[(size_t)jj*230400 + gbase + pi] = svf[pi*33+jj];
    svg_i[(size_t)jj*230400 + gbase + pi] = svi[pi*33+jj];
  }
}

// ---------------- A2: dec + sigmoid + aux (position-per-lane, decT in LDS) ----------------
__global__ __launch_bounds__(256, 5) void stage_a2(
    const float* __restrict__ svg_v, const unsigned char* __restrict__ svg_i,
    const float* __restrict__ decT, const float* __restrict__ dec_b,
    const float* __restrict__ x, float* __restrict__ auxp)
{
  __shared__ float decl[6912];   // [idx][o], stride 27
  __shared__ float redbuf[256];
  const int t = threadIdx.x;
  for (int e=t; e<6912; e+=256) decl[e] = decT[e];
  __syncthreads();

  const int pos = blockIdx.x*256 + t;
  const int b = pos/900, rem = pos - b*900;
  const int oh = rem/30, ow = rem - (rem/30)*30;

  float d[27];
  #pragma unroll
  for (int o=0;o<27;++o) d[o] = dec_b[o];
  for (int jj=0; jj<32; ++jj){
    float v  = svg_v[(size_t)jj*230400 + pos];
    int  idx = (int)svg_i[(size_t)jj*230400 + pos];
    const float* wr = decl + idx*27;
    #pragma unroll
    for (int o=0;o<27;++o) d[o] = fmaf(v, wr[o], d[o]);
  }
  float acc = 0.f;
  #pragma unroll
  for (int o=0;o<27;++o){
    int ci = o/9, r2 = (o - ci*9)/3, c2 = o%3;
    float tg = x[((b*3+ci)*32 + (oh+r2))*32 + (ow+c2)];
    float dv = 1.f/(1.f + __expf(-d[o]));
    float df = tg - dv;
    acc = fmaf(df, df, acc);
  }
  redbuf[t]=acc; __syncthreads();
  for (int off=128; off; off>>=1){ if (t<off) redbuf[t]+=redbuf[t+off]; __syncthreads(); }
  if (t==0) auxp[blockIdx.x] = redbuf[0];
}

__global__ void aux_reduce(const float* __restrict__ p, float* __restrict__ outp){
  __shared__ float s[256];
  int t = threadIdx.x; float a=0.f;
  for (int i=t; i<900; i+=256) a += p[i];
  s[t]=a; __syncthreads();
  for (int off=128; off; off>>=1){ if (t<off) s[t]+=s[t+off]; __syncthreads(); }
  if (t==0) outp[25856] = s[0] / 6220800.0f;
}

// ---------------- A3: red -> h0 channel-major (position-per-lane, redT in LDS) ----------------
// (512,2): same launch-bounds fix as a1 — the old (512,4) forced a 64-reg
// budget while v[32]+a[32] alone need 64+ -> spill.
__global__ __launch_bounds__(512, 2) void stage_a3(
    const float* __restrict__ svg_v, const unsigned char* __restrict__ svg_i,
    const float* __restrict__ redT, const float* __restrict__ red_b,
    float* __restrict__ h0T)
{
  __shared__ float redl[256*65];   // [idx][o] stride 65 -> bank (idx+o)%32
  const int t = threadIdx.x;
  for (int e=t; e<16384; e+=512) redl[(e>>6)*65 + (e&63)] = redT[e];
  __syncthreads();

  const size_t pos = (size_t)blockIdx.x*512 + t;
  float v[32]; int a[32];
  #pragma unroll
  for (int jj=0;jj<32;++jj) v[jj] = svg_v[(size_t)jj*230400 + pos];
  #pragma unroll
  for (int jj=0;jj<32;++jj) a[jj] = (int)svg_i[(size_t)jj*230400 + pos]*65;

  #pragma unroll 2
  for (int o=0;o<64;++o){
    float acc0 = red_b[o], acc1 = 0.f;
    #pragma unroll
    for (int jj=0;jj<32;jj+=2){
      acc0 = fmaf(v[jj],   redl[a[jj]+o],   acc0);
      acc1 = fmaf(v[jj+1], redl[a[jj+1]+o], acc1);
    }
    h0T[(size_t)o*230400 + pos] = acc0 + acc1;
  }
}

// ---------------- BN stats ----------------
__global__ void bn_cm64(const float* __restrict__ h0T, float* __restrict__ psum,
                        float* __restrict__ psq){
  __shared__ float ls[256], lq[256];
  const int t = threadIdx.x;
  const float4* p = (const float4*)(h0T + (size_t)blockIdx.x*230400);
  float s=0.f, q=0.f;
  for (int i=t; i<57600; i+=256){
    float4 f = p[i];
    s += f.x+f.y+f.z+f.w;
    q = fmaf(f.x,f.x,q); q = fmaf(f.y,f.y,q); q = fmaf(f.z,f.z,q); q = fmaf(f.w,f.w,q);
  }
  ls[t]=s; lq[t]=q; __syncthreads();
  for (int off=128; off; off>>=1){
    if (t<off){ ls[t]+=ls[t+off]; lq[t]+=lq[t+off]; } __syncthreads();
  }
  if (t==0){ psum[blockIdx.x]=ls[0]; psq[blockIdx.x]=lq[0]; }
}

template<int C, int BD>
__global__ void bn_partial(const float* __restrict__ in, float* __restrict__ psum,
                           float* __restrict__ psq, int npos){
  constexpr int GPB = BD / C;
  const int t = threadIdx.x;
  const int c = t % C, g = t / C;
  float s=0.f, q=0.f;
  for (int i = blockIdx.x*GPB + g; i < npos; i += gridDim.x*GPB){
    float v = in[i*C + c];
    s += v; q = fmaf(v, v, q);
  }
  __shared__ float ls[BD], lq[BD];
  ls[t]=s; lq[t]=q; __syncthreads();
  for (int off=BD/2; off>=C; off>>=1){
    if (t<off){ ls[t]+=ls[t+off]; lq[t]+=lq[t+off]; }
    __syncthreads();
  }
  if (t<C){ psum[blockIdx.x*C+t]=ls[t]; psq[blockIdx.x*C+t]=lq[t]; }
}

template<int C>
__global__ void bn_final(const float* __restrict__ ps, const float* __restrict__ pq,
                         const float* __restrict__ g, const float* __restrict__ b2,
                         float* __restrict__ sc, float* __restrict__ sh, float inv_n, int G){
  int t = threadIdx.x;
  if (t >= C) return;
  float s=0.f, q=0.f;
  for (int i=0;i<G;++i){ s += ps[i*C+t]; q += pq[i*C+t]; }
  float m = s*inv_n;
  float v = fmaf(q, inv_n, -m*m);
  float rs = rsqrtf(v + 1e-5f);
  float scale = g[t]*rs;
  sc[t] = scale;
  sh[t] = fmaf(-m, scale, b2[t]);
}

// ---------------- generic 3x3 valid conv, fused BN+ReLU in, optional maxpool ----------------
template<int CIN,int COUT,int HIN,int WIN,bool POOL,int NPOS>
DEV_INLINE void conv_compute(const float* lds, const float* __restrict__ wt,
                             const float* __restrict__ bias, float* __restrict__ out,
                             int b, int orow, int iw0, int co, bool cok)
{
  constexpr int S = lds_stride(WIN);
  constexpr int NROWS = POOL ? 4 : 3;
  constexpr int HC = HIN-2, WC = WIN-2;
  constexpr int IVL = roundup4(NPOS+2);
  float acc0[NPOS], acc1[POOL?NPOS:1];
  const float bv = bias[co];
  #pragma unroll
  for (int p=0;p<NPOS;++p) acc0[p]=bv;
  if (POOL){
    #pragma unroll
    for (int p=0;p<NPOS;++p) acc1[p]=bv;
  }
  for (int ci=0; ci<CIN; ++ci){
    #pragma unroll
    for (int r=0;r<NROWS;++r){
      float iv[IVL];
      const float4* rp = (const float4*)(lds + (r*CIN+ci)*S + iw0);
      #pragma unroll
      for (int q=0;q<IVL/4;++q){
        float4 f = rp[q];
        iv[4*q+0]=f.x; iv[4*q+1]=f.y; iv[4*q+2]=f.z; iv[4*q+3]=f.w;
      }
      #pragma unroll
      for (int kw=0;kw<3;++kw){
        if (!POOL || r < 3){
          float w = wt[((r*3+kw)*CIN+ci)*COUT + co];
          #pragma unroll
          for (int p=0;p<NPOS;++p) acc0[p] = fmaf(iv[p+kw], w, acc0[p]);
        }
        if (POOL && r >= 1){
          float w = wt[(((r-1)*3+kw)*CIN+ci)*COUT + co];
          #pragma unroll
          for (int p=0;p<NPOS;++p) acc1[p] = fmaf(iv[p+kw], w, acc1[p]);
        }
      }
    }
  }
  if (!cok) return;
  if (POOL){
    constexpr int HP=HC/2, WP=WC/2;
    #pragma unroll
    for (int q=0;q<NPOS/2;++q){
      float m = fmaxf(fmaxf(acc0[2*q],acc0[2*q+1]), fmaxf(acc1[2*q],acc1[2*q+1]));
      out[((b*HP + orow)*WP + (iw0>>1) + q)*COUT + co] = m;
    }
  } else {
    #pragma unroll
    for (int p=0;p<NPOS;++p)
      out[((b*HC + orow)*WC + iw0 + p)*COUT + co] = acc0[p];
  }
}

template<int CIN,int COUT,int HIN,int WIN,bool POOL,bool CMIN>
__global__ __launch_bounds__(256) void conv3x3(
    const float* __restrict__ in, const float* __restrict__ wt,
    const float* __restrict__ bias, const float* __restrict__ scale,
    const float* __restrict__ shift, float* __restrict__ out)
{
  constexpr int WC = WIN-2;
  constexpr int NROWS = POOL ? 4 : 3;
  constexpr int S = lds_stride(WIN);
  constexpr size_t NPIX = (size_t)256*HIN*WIN;
  __shared__ float4 lds4[(NROWS*CIN*S)/4];
  float* lds = (float*)lds4;

  const int b = blockIdx.y, orow = blockIdx.x;
  const int ih0 = POOL ? 2*orow : orow;
  const float* src = in + ((long)(b*HIN + ih0))*WIN*CIN;
  for (int e = threadIdx.x; e < NROWS*WIN*CIN; e += 256){
    int c, iw, r; float v;
    if constexpr (CMIN){
      iw = e % WIN; int rest = e / WIN; c = rest % CIN; r = rest / CIN;
      v = in[(size_t)c*NPIX + ((size_t)b*HIN + ih0 + r)*WIN + iw];
    } else {
      c = e % CIN; int rest = e / CIN; iw = rest % WIN; r = rest / WIN;
      v = src[e];
    }
    v = fmaxf(fmaf(v, scale[c], shift[c]), 0.f);
    lds[(r*CIN + c)*S + iw] = v;
  }
  __syncthreads();

  const int wid = threadIdx.x>>6, lane = threadIdx.x&63;
  constexpr int NCHUNK = (COUT+63)/64;
  constexpr int NSTRIP = (NCHUNK<=2 && WC>4) ? 2 : 1;
  constexpr int NPOS0  = (NSTRIP==2) ? ((WC/2+3)&~3) : WC;
  if (wid >= NCHUNK*NSTRIP) return;
  int chunk, strip;
  if (NSTRIP==2){ chunk = wid & 1; strip = wid >> 1; } else { chunk = wid; strip = 0; }
  const int co = chunk*64 + lane;
  const bool cok = co < COUT;
  const int coc = cok ? co : (COUT-1);
  if (strip==0){
    conv_compute<CIN,COUT,HIN,WIN,POOL,NPOS0>(lds, wt, bias, out, b, orow, 0, coc, cok);
  } else {
    if constexpr (NSTRIP==2){
      constexpr int NPOS1 = WC - NPOS0;
      conv_compute<CIN,COUT,HIN,WIN,POOL,NPOS1>(lds, wt, bias, out, b, orow, NPOS0, coc, cok);
    }
  }
}

// ---------------- final: bnc + FC + argmax ----------------
__global__ __launch_bounds__(256) void fc_kernel(
    const float* __restrict__ a5, const float* __restrict__ scale, const float* __restrict__ shift,
    const float* __restrict__ fcT, const float* __restrict__ fc_b, float* __restrict__ outp)
{
  __shared__ float f[1024];
  __shared__ float part[256];
  __shared__ float lg[128];
  const int b = blockIdx.x, t = threadIdx.x;
  for (int e=t; e<1024; e+=256){
    int c = e & 255, hw = e >> 8;
    float v = a5[b*1024 + e];
    f[c*4 + hw] = fmaf(v, scale[c], shift[c]);
  }
  __syncthreads();
  const int o = t & 127, half = t >> 7;
  float s = 0.f;
  if (o < 100){
    const float* fp = f + half*512;
    const float* wp = fcT + half*512*100 + o;
    for (int j=0;j<512;++j) s = fmaf(fp[j], wp[j*100], s);
  }
  part[t] = s; __syncthreads();
  if (t < 128){
    float logit = part[t] + part[t+128] + ((t<100)? fc_b[t] : 0.f);
    lg[t] = (t<100)? logit : -3.0e38f;
    if (t<100) outp[b*100 + t] = logit;
  }
  __syncthreads();
  if (t==0){
    float m = lg[0]; int mi = 0;
    for (int i=1;i<100;++i){ if (lg[i] > m){ m = lg[i]; mi = i; } }
    outp[25600 + b] = (float)mi;
  }
}

// ---------------- launch ----------------
extern "C" void kernel_launch(void* const* d_in, const int* in_sizes, int n_in,
                              void* d_out, int out_size, void* d_ws, size_t ws_size,
                              hipStream_t stream)
{
  (void)in_sizes; (void)n_in; (void)out_size;
  const float* x     = (const float*)d_in[0];
  const float* enc_w = (const float*)d_in[1];
  const float* enc_b = (const float*)d_in[2];
  const float* dec_w = (const float*)d_in[3];
  const float* dec_b = (const float*)d_in[4];
  const float* red_w = (const float*)d_in[5];
  const float* red_b = (const float*)d_in[6];
  const float* bn1_g = (const float*)d_in[7];  const float* bn1_b = (const float*)d_in[8];
  const float* c1w   = (const float*)d_in[9];  const float* c1b   = (const float*)d_in[10];
  const float* bn2_g = (const float*)d_in[11]; const float* bn2_b = (const float*)d_in[12];
  const float* c2w   = (const float*)d_in[13]; const float* c2b   = (const float*)d_in[14];
  const float* bn3_g = (const float*)d_in[15]; const float* bn3_b = (const float*)d_in[16];
  const float* c3w   = (const float*)d_in[17]; const float* c3b   = (const float*)d_in[18];
  const float* bn4_g = (const float*)d_in[19]; const float* bn4_b = (const float*)d_in[20];
  const float* c4w   = (const float*)d_in[21]; const float* c4b   = (const float*)d_in[22];
  const float* bn5_g = (const float*)d_in[23]; const float* bn5_b = (const float*)d_in[24];
  const float* c5w   = (const float*)d_in[25]; const float* c5b   = (const float*)d_in[26];
  const float* bnc_g = (const float*)d_in[27]; const float* bnc_b = (const float*)d_in[28];
  const float* fc_w  = (const float*)d_in[29]; const float* fc_b  = (const float*)d_in[30];
  const int*   kp    = (const int*)d_in[31];
  float* out = (float*)d_out;
  float* ws  = (float*)d_ws;

  // ---- workspace layout (floats) ----
  constexpr size_t OFF_ENCT = 0;
  constexpr size_t OFF_DECT = 7168;
  constexpr size_t OFF_REDT = 14336;
  constexpr size_t OFF_FCT  = OFF_REDT + 16384;
  constexpr size_t OFF_WT1  = OFF_FCT + 102400;
  constexpr size_t OFF_WT2  = OFF_WT1 + 55296;
  constexpr size_t OFF_WT3  = OFF_WT2 + 110592;
  constexpr size_t OFF_WT4  = OFF_WT3 + 184320;
  constexpr size_t OFF_WT5  = OFF_WT4 + 276480;
  constexpr size_t OFF_SS1  = OFF_WT5 + 442368;
  constexpr size_t OFF_SS2  = OFF_SS1 + 128;
  constexpr size_t OFF_SS3  = OFF_SS2 + 192;
  constexpr size_t OFF_SS4  = OFF_SS3 + 256;
  constexpr size_t OFF_SS5  = OFF_SS4 + 320;
  constexpr size_t OFF_SSC  = OFF_SS5 + 384;
  constexpr size_t OFF_PSUM = OFF_SSC + 512;
  constexpr size_t OFF_PSQ  = OFF_PSUM + 49152;
  constexpr size_t OFF_AUX  = OFF_PSQ + 49152;
  constexpr size_t OFF_A1   = OFF_AUX + 7936;
  constexpr size_t OFF_H0   = OFF_A1 + 4816896;       // h0T channel-major [64][230400]
  constexpr size_t OFF_A2   = OFF_H0;                 // overlays dead h0
  constexpr size_t OFF_A3   = OFF_A2 + 4718592;
  constexpr size_t OFF_A4   = OFF_A3 + 4096000;
  constexpr size_t OFF_A5   = OFF_A4 + 786432;
  constexpr size_t OFF_SVV  = OFF_H0 + 14745600;      // 32*230400
  constexpr size_t OFF_SVI  = OFF_SVV + 7372800;      // bytes region
  constexpr size_t TOTALF   = OFF_SVI + 1843200;
  if (ws_size < TOTALF*sizeof(float)) return;

  float* encTg = ws + OFF_ENCT;
  float* decT = ws + OFF_DECT;  float* redT = ws + OFF_REDT;  float* fcT = ws + OFF_FCT;
  float* WT1 = ws + OFF_WT1; float* WT2 = ws + OFF_WT2; float* WT3 = ws + OFF_WT3;
  float* WT4 = ws + OFF_WT4; float* WT5 = ws + OFF_WT5;
  float* ss1 = ws + OFF_SS1; float* ss2 = ws + OFF_SS2; float* ss3 = ws + OFF_SS3;
  float* ss4 = ws + OFF_SS4; float* ss5 = ws + OFF_SS5; float* ssc = ws + OFF_SSC;
  float* psum = ws + OFF_PSUM; float* psq = ws + OFF_PSQ; float* auxp = ws + OFF_AUX;
  float* a1 = ws + OFF_A1; float* h0 = ws + OFF_H0;
  float* a2 = ws + OFF_A2; float* a3 = ws + OFF_A3; float* a4 = ws + OFF_A4; float* a5 = ws + OFF_A5;
  float* svv = ws + OFF_SVV;
  unsigned char* svi = (unsigned char*)(ws + OFF_SVI);

  const int G = 192;

  prep_all<<<982, 256, 0, stream>>>(enc_w, encTg, dec_w, decT, red_w, redT, fc_w, fcT,
                                    c1w, WT1, c2w, WT2, c3w, WT3, c4w, WT4, c5w, WT5);

  // stage A: A1 conv+topk+compact, A2 dec/aux, A3 red->h0T
  stage_a1<<<dim3(15,256), 512, 0, stream>>>(encTg, enc_b, x, kp, svv, svi);
  stage_a2<<<900, 256, 0, stream>>>(svv, svi, decT, dec_b, x, auxp);
  aux_reduce<<<1, 256, 0, stream>>>(auxp, out);
  stage_a3<<<450, 512, 0, stream>>>(svv, svi, redT, red_b, h0);

  // bn1 (channel-major) + conv1(+pool)
  bn_cm64<<<64, 256, 0, stream>>>(h0, psum, psq);
  bn_final<64><<<1, 256, 0, stream>>>(psum, psq, bn1_g, bn1_b, ss1, ss1+64, 1.f/230400.f, 1);
  conv3x3<64,96,30,30,true,true><<<dim3(14,256), 256, 0, stream>>>(h0, WT1, c1b, ss1, ss1+64, a1);

  // bn2 + conv2
  bn_partial<96,192><<<G, 192, 0, stream>>>(a1, psum, psq, 50176);
  bn_final<96><<<1, 256, 0, stream>>>(psum, psq, bn2_g, bn2_b, ss2, ss2+96, 1.f/50176.f, G);
  conv3x3<96,128,14,14,false,false><<<dim3(12,256), 256, 0, stream>>>(a1, WT2, c2b, ss2, ss2+96, a2);

  // bn3 + conv3
  bn_partial<128,256><<<G, 256, 0, stream>>>(a2, psum, psq, 36864);
  bn_final<128><<<1, 256, 0, stream>>>(psum, psq, bn3_g, bn3_b, ss3, ss3+128, 1.f/36864.f, G);
  conv3x3<128,160,12,12,false,false><<<dim3(10,256), 256, 0, stream>>>(a2, WT3, c3b, ss3, ss3+128, a3);

  // bn4 + conv4(+pool)
  bn_partial<160,320><<<G, 320, 0, stream>>>(a3, psum, psq, 25600);
  bn_final<160><<<1, 256, 0, stream>>>(psum, psq, bn4_g, bn4_b, ss4, ss4+160, 1.f/25600.f, G);
  conv3x3<160,192,10,10,true,false><<<dim3(4,256), 256, 0, stream>>>(a3, WT4, c4b, ss4, ss4+160, a4);

  // bn5 + conv5
  bn_partial<192,192><<<G, 192, 0, stream>>>(a4, psum, psq, 4096);
  bn_final<192><<<1, 256, 0, stream>>>(psum, psq, bn5_g, bn5_b, ss5, ss5+192, 1.f/4096.f, G);
  conv3x3<192,256,4,4,false,false><<<dim3(2,256), 256, 0, stream>>>(a4, WT5, c5b, ss5, ss5+192, a5);

  // bnc + fc + argmax
  bn_partial<256,256><<<G, 256, 0, stream>>>(a5, psum, psq, 1024);
  bn_final<256><<<1, 256, 0, stream>>>(psum, psq, bnc_g, bnc_b, ssc, ssc+256, 1.f/1024.f, G);
  fc_kernel<<<256, 256, 0, stream>>>(a5, ssc, ssc+256, fcT, fc_b, out);
}